// Round 4
// baseline (7288.556 us; speedup 1.0000x reference)
//
#include <hip/hip_runtime.h>

// NeuralCDE B=1024,S=64,F=16,H=128. Persistent fp32 kernel, NB=4, 256 wgs.
// Round 3 (resubmit — round-3 bench hit GPUAcquisitionTimeout, never ran):
// lgkm-only barriers (W2 prefetch survives barriers), RK-update fused into
// GEMM1 (all 16 waves, j-split + shfl), 6/32 W2 k-chunks persisted in
// registers (L2 traffic x0.8125).

#define NT 1024
#define PERSIST 6

// Pack W2[2048][128] -> PW2 slot (kc*2+j)*1024 + t = float4{W2[row=t*2+j, k=kc*4..+3]}
__global__ void pack_w2_kernel(const float* __restrict__ W2, float4* __restrict__ PW2) {
    const int q = blockIdx.x * blockDim.x + threadIdx.x;   // 0..65535
    const int t = q & 1023, j = (q >> 10) & 1, kc = q >> 11;
    PW2[q] = *(const float4*)&W2[((t * 2 + j) << 7) + (kc << 2)];
}

__device__ __forceinline__ void lgkm_barrier() {
    // LDS-only fence + barrier: leaves global (vmcnt) prefetches in flight.
    asm volatile("s_waitcnt lgkmcnt(0)\n\ts_barrier" ::: "memory");
}

template<bool PACKED>
__global__ __launch_bounds__(NT, 4) void cde_kernel(
    const float* __restrict__ x,  const float* __restrict__ W1,
    const float* __restrict__ b1, const float* __restrict__ W2,
    const float* __restrict__ b2, const float* __restrict__ Wi,
    const float* __restrict__ bi, const float4* __restrict__ PW2,
    float* __restrict__ out)
{
    // LDS: 64K + 16K + 2K + 2K + 8K + 1K = 93 KiB
    __shared__ float pW1[16384];   // pW1[j4*512 + k*4 + jj] = W1[k][j4*4+jj]
    __shared__ float sx[4096];     // x slice [b][s][f]
    __shared__ float zB[512];      // z [b][k]
    __shared__ float hB[512];      // state h [b][j]
    __shared__ float skS[2048];    // k1..k4 [s][b][j]
    __shared__ float sdX[256];     // dX at 4 RK nodes [node][b][f]

    const int t = threadIdx.x;
    const int b_base = blockIdx.x * 4;
    const float dt = 1.0f / 63.0f, rdt = 63.0f;
    const float c13 = dt * (1.0f / 3.0f);

    for (int idx = t; idx < 4096; idx += NT) sx[idx] = x[(size_t)b_base * 1024 + idx];
    for (int idx = t; idx < 16384; idx += NT) {
        const int j4 = idx >> 9, k = (idx >> 2) & 127, jj = idx & 3;
        pW1[idx] = W1[k * 128 + j4 * 4 + jj];
    }
    __syncthreads();

    // h0 = x[:,0] @ Wi^T + bi
    if (t < 512) {
        const int j = t & 127, b = t >> 7;
        float acc = bi[j];
#pragma unroll
        for (int f = 0; f < 16; ++f) acc = fmaf(Wi[j * 16 + f], sx[b * 1024 + f], acc);
        hB[b * 128 + j] = acc;
    }

    // GEMM1 mapping: wave w, lane l -> batch gb=w>>2, k=gk, j-half jh
    const int w = t >> 6, l = t & 63;
    const int gb   = w >> 2;
    const int gk   = ((w & 3) << 5) | (l & 31);
    const int jh16 = (l >> 5) << 4;             // j4 base: 0 or 16
    const float b1v = b1[gk];
    const float2 bb = *(const float2*)&b2[t * 2];

    const float4* pw  = PW2 + t;
    const float4* r0p = (const float4*)W2 + t * 64;
    const float4* r1p = r0p + 32;

    // persist first PERSIST k-chunks of this thread's two W2 rows in registers
    float4 wra[PERSIST], wrb[PERSIST];
#pragma unroll
    for (int kc = 0; kc < PERSIST; ++kc) {
        if (PACKED) { wra[kc] = pw[kc * 2048]; wrb[kc] = pw[kc * 2048 + 1024]; }
        else        { wra[kc] = r0p[kc];       wrb[kc] = r1p[kc]; }
    }
    // loop-carried stream prefetch (chunk PERSIST), stays in flight across barriers
    float4 na = PACKED ? pw[PERSIST * 2048]        : r0p[PERSIST];
    float4 nb = PACKED ? pw[PERSIST * 2048 + 1024] : r1p[PERSIST];
    __syncthreads();

    for (int i = 0; i < 63; ++i) {
#pragma unroll
        for (int s = 0; s < 4; ++s) {
            if (s == 0 && t < 256) {
                // Hermite backward-difference coeffs -> dX at 4 RK nodes
                const int f = t & 15, b = (t >> 4) & 3, sn = t >> 6;
                const float* xb = &sx[b * 1024];
                const float x0  = xb[i * 16 + f];
                const float x1  = xb[(i + 1) * 16 + f];
                const float seg = (x1 - x0) * rdt;
                const float m0  = (i == 0) ? seg : (x0 - xb[(i - 1) * 16 + f]) * rdt;
                const float c   = (2.0f * seg - 2.0f * m0) * rdt;
                const float d   = (m0 - seg) * rdt * rdt;
                const float ft  = (float)sn * c13;
                sdX[(sn * 4 + b) * 16 + f] = fmaf(fmaf(3.0f * d, ft, 2.0f * c), ft, m0);
            }
            // ---- GEMM1 (all waves): z[b][k] = tanh(b1 + W1 hs), hs inline from h,k1..k3
            {
                float acc = 0.0f;
                const float* wp  = &pW1[(jh16 * 128 + gk) * 4];
                const float* hp  = &hB[gb * 128 + jh16 * 4];
                const float* k1p = &skS[(0 * 4 + gb) * 128 + jh16 * 4];
                const float* k2p = &skS[(1 * 4 + gb) * 128 + jh16 * 4];
                const float* k3p = &skS[(2 * 4 + gb) * 128 + jh16 * 4];
#pragma unroll
                for (int u = 0; u < 16; ++u) {
                    const float4 wv = *(const float4*)&wp[u * 512];
                    const float4 hv = *(const float4*)&hp[u * 4];
                    float hx = hv.x, hy = hv.y, hz = hv.z, hw = hv.w;
                    if (s == 1) {
                        const float4 k1 = *(const float4*)&k1p[u * 4];
                        hx = fmaf(c13, k1.x, hx); hy = fmaf(c13, k1.y, hy);
                        hz = fmaf(c13, k1.z, hz); hw = fmaf(c13, k1.w, hw);
                    } else if (s == 2) {
                        const float4 k1 = *(const float4*)&k1p[u * 4];
                        const float4 k2 = *(const float4*)&k2p[u * 4];
                        hx = fmaf(dt, k2.x, fmaf(-c13, k1.x, hx));
                        hy = fmaf(dt, k2.y, fmaf(-c13, k1.y, hy));
                        hz = fmaf(dt, k2.z, fmaf(-c13, k1.z, hz));
                        hw = fmaf(dt, k2.w, fmaf(-c13, k1.w, hw));
                    } else if (s == 3) {
                        const float4 k1 = *(const float4*)&k1p[u * 4];
                        const float4 k2 = *(const float4*)&k2p[u * 4];
                        const float4 k3 = *(const float4*)&k3p[u * 4];
                        hx = fmaf(dt, k1.x - k2.x + k3.x, hx);
                        hy = fmaf(dt, k1.y - k2.y + k3.y, hy);
                        hz = fmaf(dt, k1.z - k2.z + k3.z, hz);
                        hw = fmaf(dt, k1.w - k2.w + k3.w, hw);
                    }
                    acc = fmaf(wv.x, hx, acc); acc = fmaf(wv.y, hy, acc);
                    acc = fmaf(wv.z, hz, acc); acc = fmaf(wv.w, hw, acc);
                }
                acc += __shfl_xor(acc, 32);   // combine the two j-halves
                const float zv = tanhf(acc + b1v);
                if (l < 32) zB[gb * 128 + gk] = zv;
            }
            lgkm_barrier();

            // ---- GEMM2 + F-contraction (rows 2t, 2t+1)
            {
                float a0[4] = {0.f, 0.f, 0.f, 0.f}, a1[4] = {0.f, 0.f, 0.f, 0.f};
#pragma unroll
                for (int kc = 0; kc < PERSIST; ++kc) {
#pragma unroll
                    for (int b = 0; b < 4; ++b) {
                        const float4 z = *(const float4*)&zB[b * 128 + kc * 4];
                        a0[b] = fmaf(wra[kc].x, z.x, a0[b]); a0[b] = fmaf(wra[kc].y, z.y, a0[b]);
                        a0[b] = fmaf(wra[kc].z, z.z, a0[b]); a0[b] = fmaf(wra[kc].w, z.w, a0[b]);
                        a1[b] = fmaf(wrb[kc].x, z.x, a1[b]); a1[b] = fmaf(wrb[kc].y, z.y, a1[b]);
                        a1[b] = fmaf(wrb[kc].z, z.z, a1[b]); a1[b] = fmaf(wrb[kc].w, z.w, a1[b]);
                    }
                }
#pragma unroll
                for (int kc = PERSIST; kc < 32; ++kc) {
                    const float4 ca = na, cb = nb;
                    const int nk = (kc == 31) ? PERSIST : kc + 1;  // wrap: prefetch next stage
                    if (PACKED) { na = pw[nk * 2048]; nb = pw[nk * 2048 + 1024]; }
                    else        { na = r0p[nk];       nb = r1p[nk]; }
#pragma unroll
                    for (int b = 0; b < 4; ++b) {
                        const float4 z = *(const float4*)&zB[b * 128 + kc * 4];
                        a0[b] = fmaf(ca.x, z.x, a0[b]); a0[b] = fmaf(ca.y, z.y, a0[b]);
                        a0[b] = fmaf(ca.z, z.z, a0[b]); a0[b] = fmaf(ca.w, z.w, a0[b]);
                        a1[b] = fmaf(cb.x, z.x, a1[b]); a1[b] = fmaf(cb.y, z.y, a1[b]);
                        a1[b] = fmaf(cb.z, z.z, a1[b]); a1[b] = fmaf(cb.w, z.w, a1[b]);
                    }
                }
                const int fp = t & 7, hh = t >> 3;
                float kv[4];
#pragma unroll
                for (int b = 0; b < 4; ++b) {
                    const float2 dx2 = *(const float2*)&sdX[(s * 4 + b) * 16 + fp * 2];
                    kv[b] = (a0[b] + bb.x) * dx2.x + (a1[b] + bb.y) * dx2.y;
                    kv[b] += __shfl_xor(kv[b], 1);
                    kv[b] += __shfl_xor(kv[b], 2);
                    kv[b] += __shfl_xor(kv[b], 4);
                }
                if (fp == 0) {
#pragma unroll
                    for (int b = 0; b < 4; ++b) skS[(s * 4 + b) * 128 + hh] = kv[b];
                }
            }
            lgkm_barrier();
        }
        // ---- h update (once per time step)
        if (t < 512) {
            const int j = t & 127, b = t >> 7;
            const float k1 = skS[(0 * 4 + b) * 128 + j];
            const float k2 = skS[(1 * 4 + b) * 128 + j];
            const float k3 = skS[(2 * 4 + b) * 128 + j];
            const float k4 = skS[(3 * 4 + b) * 128 + j];
            hB[b * 128 + j] = fmaf(dt * 0.125f, k1 + 3.0f * (k2 + k3) + k4, hB[b * 128 + j]);
        }
        lgkm_barrier();
    }

    if (t < 512) {
        const int j = t & 127, b = t >> 7;
        out[(size_t)(b_base + b) * 128 + j] = hB[b * 128 + j];
    }
}

extern "C" void kernel_launch(void* const* d_in, const int* in_sizes, int n_in,
                              void* d_out, int out_size, void* d_ws, size_t ws_size,
                              hipStream_t stream)
{
    (void)in_sizes; (void)n_in; (void)out_size;
    const float* x  = (const float*)d_in[0];
    const float* W1 = (const float*)d_in[1];
    const float* b1 = (const float*)d_in[2];
    const float* W2 = (const float*)d_in[3];
    const float* b2 = (const float*)d_in[4];
    const float* Wi = (const float*)d_in[5];
    const float* bi = (const float*)d_in[6];
    float* o = (float*)d_out;
    float4* PW2 = (float4*)d_ws;
    const bool packed = (ws_size >= (size_t)(2048 * 128 * 4));

    if (packed) {
        hipLaunchKernelGGL(pack_w2_kernel, dim3(256), dim3(256), 0, stream, W2, PW2);
        hipLaunchKernelGGL(HIP_KERNEL_NAME(cde_kernel<true>), dim3(256), dim3(NT), 0, stream,
                           x, W1, b1, W2, b2, Wi, bi, PW2, o);
    } else {
        hipLaunchKernelGGL(HIP_KERNEL_NAME(cde_kernel<false>), dim3(256), dim3(NT), 0, stream,
                           x, W1, b1, W2, b2, Wi, bi, PW2, o);
    }
}

// Round 6
// 7149.965 us; speedup vs baseline: 1.0194x; 1.0194x over previous
//
#include <hip/hip_runtime.h>

// NeuralCDE B=1024,S=64,F=16,H=128. Persistent fp32 kernel, NB=4, 256 wgs.
// Round 6 (resubmit — round-5 bench hit GPUAcquisitionTimeout, never ran):
// round-3 structure (lgkm-only barriers, RK fused into GEMM1,
// register-persistent W2 chunks) with the spill bug fixed:
//   - __launch_bounds__(NT) only  (r4's ",4" arg capped VGPR at 64 -> 15.8 GB
//     of scratch traffic, 2.2x regression)
//   - PERSIST 6 -> 4 (32 VGPRs persistence, total ~100 < 128 cap)

#define NT 1024
#define PERSIST 4

// Pack W2[2048][128] -> PW2 slot (kc*2+j)*1024 + t = float4{W2[row=t*2+j, k=kc*4..+3]}
__global__ void pack_w2_kernel(const float* __restrict__ W2, float4* __restrict__ PW2) {
    const int q = blockIdx.x * blockDim.x + threadIdx.x;   // 0..65535
    const int t = q & 1023, j = (q >> 10) & 1, kc = q >> 11;
    PW2[q] = *(const float4*)&W2[((t * 2 + j) << 7) + (kc << 2)];
}

__device__ __forceinline__ void lgkm_barrier() {
    // LDS-only fence + barrier: leaves global (vmcnt) prefetches in flight.
    asm volatile("s_waitcnt lgkmcnt(0)\n\ts_barrier" ::: "memory");
}

template<bool PACKED>
__global__ __launch_bounds__(NT) void cde_kernel(
    const float* __restrict__ x,  const float* __restrict__ W1,
    const float* __restrict__ b1, const float* __restrict__ W2,
    const float* __restrict__ b2, const float* __restrict__ Wi,
    const float* __restrict__ bi, const float4* __restrict__ PW2,
    float* __restrict__ out)
{
    // LDS: 64K + 16K + 2K + 2K + 8K + 1K = 93 KiB
    __shared__ float pW1[16384];   // pW1[j4*512 + k*4 + jj] = W1[k][j4*4+jj]
    __shared__ float sx[4096];     // x slice [b][s][f]
    __shared__ float zB[512];      // z [b][k]
    __shared__ float hB[512];      // state h [b][j]
    __shared__ float skS[2048];    // k1..k4 [s][b][j]
    __shared__ float sdX[256];     // dX at 4 RK nodes [node][b][f]

    const int t = threadIdx.x;
    const int b_base = blockIdx.x * 4;
    const float dt = 1.0f / 63.0f, rdt = 63.0f;
    const float c13 = dt * (1.0f / 3.0f);

    for (int idx = t; idx < 4096; idx += NT) sx[idx] = x[(size_t)b_base * 1024 + idx];
    for (int idx = t; idx < 16384; idx += NT) {
        const int j4 = idx >> 9, k = (idx >> 2) & 127, jj = idx & 3;
        pW1[idx] = W1[k * 128 + j4 * 4 + jj];
    }
    __syncthreads();

    // h0 = x[:,0] @ Wi^T + bi
    if (t < 512) {
        const int j = t & 127, b = t >> 7;
        float acc = bi[j];
#pragma unroll
        for (int f = 0; f < 16; ++f) acc = fmaf(Wi[j * 16 + f], sx[b * 1024 + f], acc);
        hB[b * 128 + j] = acc;
    }

    // GEMM1 mapping: wave w, lane l -> batch gb=w>>2, k=gk, j-half jh
    const int w = t >> 6, l = t & 63;
    const int gb   = w >> 2;
    const int gk   = ((w & 3) << 5) | (l & 31);
    const int jh16 = (l >> 5) << 4;             // j4 base: 0 or 16
    const float b1v = b1[gk];
    const float2 bb = *(const float2*)&b2[t * 2];

    const float4* pw  = PW2 + t;
    const float4* r0p = (const float4*)W2 + t * 64;
    const float4* r1p = r0p + 32;

    // persist first PERSIST k-chunks of this thread's two W2 rows in registers
    float4 wra[PERSIST], wrb[PERSIST];
#pragma unroll
    for (int kc = 0; kc < PERSIST; ++kc) {
        if (PACKED) { wra[kc] = pw[kc * 2048]; wrb[kc] = pw[kc * 2048 + 1024]; }
        else        { wra[kc] = r0p[kc];       wrb[kc] = r1p[kc]; }
    }
    // loop-carried stream prefetch (chunk PERSIST), stays in flight across barriers
    float4 na = PACKED ? pw[PERSIST * 2048]        : r0p[PERSIST];
    float4 nb = PACKED ? pw[PERSIST * 2048 + 1024] : r1p[PERSIST];
    __syncthreads();

    for (int i = 0; i < 63; ++i) {
#pragma unroll
        for (int s = 0; s < 4; ++s) {
            if (s == 0 && t < 256) {
                // Hermite backward-difference coeffs -> dX at 4 RK nodes
                const int f = t & 15, b = (t >> 4) & 3, sn = t >> 6;
                const float* xb = &sx[b * 1024];
                const float x0  = xb[i * 16 + f];
                const float x1  = xb[(i + 1) * 16 + f];
                const float seg = (x1 - x0) * rdt;
                const float m0  = (i == 0) ? seg : (x0 - xb[(i - 1) * 16 + f]) * rdt;
                const float c   = (2.0f * seg - 2.0f * m0) * rdt;
                const float d   = (m0 - seg) * rdt * rdt;
                const float ft  = (float)sn * c13;
                sdX[(sn * 4 + b) * 16 + f] = fmaf(fmaf(3.0f * d, ft, 2.0f * c), ft, m0);
            }
            // ---- GEMM1 (all waves): z[b][k] = tanh(b1 + W1 hs), hs inline from h,k1..k3
            {
                float acc = 0.0f;
                const float* wp  = &pW1[(jh16 * 128 + gk) * 4];
                const float* hp  = &hB[gb * 128 + jh16 * 4];
                const float* k1p = &skS[(0 * 4 + gb) * 128 + jh16 * 4];
                const float* k2p = &skS[(1 * 4 + gb) * 128 + jh16 * 4];
                const float* k3p = &skS[(2 * 4 + gb) * 128 + jh16 * 4];
#pragma unroll
                for (int u = 0; u < 16; ++u) {
                    const float4 wv = *(const float4*)&wp[u * 512];
                    const float4 hv = *(const float4*)&hp[u * 4];
                    float hx = hv.x, hy = hv.y, hz = hv.z, hw = hv.w;
                    if (s == 1) {
                        const float4 k1 = *(const float4*)&k1p[u * 4];
                        hx = fmaf(c13, k1.x, hx); hy = fmaf(c13, k1.y, hy);
                        hz = fmaf(c13, k1.z, hz); hw = fmaf(c13, k1.w, hw);
                    } else if (s == 2) {
                        const float4 k1 = *(const float4*)&k1p[u * 4];
                        const float4 k2 = *(const float4*)&k2p[u * 4];
                        hx = fmaf(dt, k2.x, fmaf(-c13, k1.x, hx));
                        hy = fmaf(dt, k2.y, fmaf(-c13, k1.y, hy));
                        hz = fmaf(dt, k2.z, fmaf(-c13, k1.z, hz));
                        hw = fmaf(dt, k2.w, fmaf(-c13, k1.w, hw));
                    } else if (s == 3) {
                        const float4 k1 = *(const float4*)&k1p[u * 4];
                        const float4 k2 = *(const float4*)&k2p[u * 4];
                        const float4 k3 = *(const float4*)&k3p[u * 4];
                        hx = fmaf(dt, k1.x - k2.x + k3.x, hx);
                        hy = fmaf(dt, k1.y - k2.y + k3.y, hy);
                        hz = fmaf(dt, k1.z - k2.z + k3.z, hz);
                        hw = fmaf(dt, k1.w - k2.w + k3.w, hw);
                    }
                    acc = fmaf(wv.x, hx, acc); acc = fmaf(wv.y, hy, acc);
                    acc = fmaf(wv.z, hz, acc); acc = fmaf(wv.w, hw, acc);
                }
                acc += __shfl_xor(acc, 32);   // combine the two j-halves
                const float zv = tanhf(acc + b1v);
                if (l < 32) zB[gb * 128 + gk] = zv;
            }
            lgkm_barrier();

            // ---- GEMM2 + F-contraction (rows 2t, 2t+1)
            {
                float a0[4] = {0.f, 0.f, 0.f, 0.f}, a1[4] = {0.f, 0.f, 0.f, 0.f};
#pragma unroll
                for (int kc = 0; kc < PERSIST; ++kc) {
#pragma unroll
                    for (int b = 0; b < 4; ++b) {
                        const float4 z = *(const float4*)&zB[b * 128 + kc * 4];
                        a0[b] = fmaf(wra[kc].x, z.x, a0[b]); a0[b] = fmaf(wra[kc].y, z.y, a0[b]);
                        a0[b] = fmaf(wra[kc].z, z.z, a0[b]); a0[b] = fmaf(wra[kc].w, z.w, a0[b]);
                        a1[b] = fmaf(wrb[kc].x, z.x, a1[b]); a1[b] = fmaf(wrb[kc].y, z.y, a1[b]);
                        a1[b] = fmaf(wrb[kc].z, z.z, a1[b]); a1[b] = fmaf(wrb[kc].w, z.w, a1[b]);
                    }
                }
#pragma unroll
                for (int kc = PERSIST; kc < 32; ++kc) {
                    const float4 ca = na, cb = nb;
                    const int nk = (kc == 31) ? PERSIST : kc + 1;  // wrap: prefetch next stage
                    if (PACKED) { na = pw[nk * 2048]; nb = pw[nk * 2048 + 1024]; }
                    else        { na = r0p[nk];       nb = r1p[nk]; }
#pragma unroll
                    for (int b = 0; b < 4; ++b) {
                        const float4 z = *(const float4*)&zB[b * 128 + kc * 4];
                        a0[b] = fmaf(ca.x, z.x, a0[b]); a0[b] = fmaf(ca.y, z.y, a0[b]);
                        a0[b] = fmaf(ca.z, z.z, a0[b]); a0[b] = fmaf(ca.w, z.w, a0[b]);
                        a1[b] = fmaf(cb.x, z.x, a1[b]); a1[b] = fmaf(cb.y, z.y, a1[b]);
                        a1[b] = fmaf(cb.z, z.z, a1[b]); a1[b] = fmaf(cb.w, z.w, a1[b]);
                    }
                }
                const int fp = t & 7, hh = t >> 3;
                float kv[4];
#pragma unroll
                for (int b = 0; b < 4; ++b) {
                    const float2 dx2 = *(const float2*)&sdX[(s * 4 + b) * 16 + fp * 2];
                    kv[b] = (a0[b] + bb.x) * dx2.x + (a1[b] + bb.y) * dx2.y;
                    kv[b] += __shfl_xor(kv[b], 1);
                    kv[b] += __shfl_xor(kv[b], 2);
                    kv[b] += __shfl_xor(kv[b], 4);
                }
                if (fp == 0) {
#pragma unroll
                    for (int b = 0; b < 4; ++b) skS[(s * 4 + b) * 128 + hh] = kv[b];
                }
            }
            lgkm_barrier();
        }
        // ---- h update (once per time step)
        if (t < 512) {
            const int j = t & 127, b = t >> 7;
            const float k1 = skS[(0 * 4 + b) * 128 + j];
            const float k2 = skS[(1 * 4 + b) * 128 + j];
            const float k3 = skS[(2 * 4 + b) * 128 + j];
            const float k4 = skS[(3 * 4 + b) * 128 + j];
            hB[b * 128 + j] = fmaf(dt * 0.125f, k1 + 3.0f * (k2 + k3) + k4, hB[b * 128 + j]);
        }
        lgkm_barrier();
    }

    if (t < 512) {
        const int j = t & 127, b = t >> 7;
        out[(size_t)(b_base + b) * 128 + j] = hB[b * 128 + j];
    }
}

extern "C" void kernel_launch(void* const* d_in, const int* in_sizes, int n_in,
                              void* d_out, int out_size, void* d_ws, size_t ws_size,
                              hipStream_t stream)
{
    (void)in_sizes; (void)n_in; (void)out_size;
    const float* x  = (const float*)d_in[0];
    const float* W1 = (const float*)d_in[1];
    const float* b1 = (const float*)d_in[2];
    const float* W2 = (const float*)d_in[3];
    const float* b2 = (const float*)d_in[4];
    const float* Wi = (const float*)d_in[5];
    const float* bi = (const float*)d_in[6];
    float* o = (float*)d_out;
    float4* PW2 = (float4*)d_ws;
    const bool packed = (ws_size >= (size_t)(2048 * 128 * 4));

    if (packed) {
        hipLaunchKernelGGL(pack_w2_kernel, dim3(256), dim3(256), 0, stream, W2, PW2);
        hipLaunchKernelGGL(HIP_KERNEL_NAME(cde_kernel<true>), dim3(256), dim3(NT), 0, stream,
                           x, W1, b1, W2, b2, Wi, bi, PW2, o);
    } else {
        hipLaunchKernelGGL(HIP_KERNEL_NAME(cde_kernel<false>), dim3(256), dim3(NT), 0, stream,
                           x, W1, b1, W2, b2, Wi, bi, PW2, o);
    }
}

// Round 7
// 6452.216 us; speedup vs baseline: 1.1296x; 1.1081x over previous
//
#include <hip/hip_runtime.h>

// NeuralCDE B=1024,S=64,F=16,H=128. Persistent fp32 kernel, NB=4, 256 wgs.
// Round 7: r2 structure (proven 3276us, VGPR=52, no spill) + register-LEAN
// deltas only. r4/r6 post-mortem: compiler caps this kernel at 64 VGPR
// regardless of launch_bounds; W2 register-persistence arrays spill to
// scratch (15 GB HBM traffic). So: NO persistence. Deltas vs r2:
//   - all-wave GEMM1 with RK stage-update fused (r6-verified math)
//   - lgkm-only barriers + W2 chunk loads issued BEFORE the barrier
//   - depth-2 in-loop W2 prefetch
//   - amdgpu_waves_per_eu(4,4): truthful (95KB LDS -> 1 WG/CU = 4 waves/EU),
//     should set VGPR budget to 128 and prevent any silent 64-cap spill.

#define NT 1024

// Pack W2[2048][128] -> PW2 slot (kc*2+j)*1024 + t = float4{W2[row=t*2+j, k=kc*4..+3]}
__global__ void pack_w2_kernel(const float* __restrict__ W2, float4* __restrict__ PW2) {
    const int q = blockIdx.x * blockDim.x + threadIdx.x;   // 0..65535
    const int t = q & 1023, j = (q >> 10) & 1, kc = q >> 11;
    PW2[q] = *(const float4*)&W2[((t * 2 + j) << 7) + (kc << 2)];
}

__device__ __forceinline__ void lgkm_barrier() {
    // LDS-only fence + barrier: leaves global (vmcnt) loads in flight.
    asm volatile("s_waitcnt lgkmcnt(0)\n\ts_barrier" ::: "memory");
}

template<bool PACKED>
__global__ __launch_bounds__(NT) __attribute__((amdgpu_waves_per_eu(4, 4)))
void cde_kernel(
    const float* __restrict__ x,  const float* __restrict__ W1,
    const float* __restrict__ b1, const float* __restrict__ W2,
    const float* __restrict__ b2, const float* __restrict__ Wi,
    const float* __restrict__ bi, const float4* __restrict__ PW2,
    float* __restrict__ out)
{
    // LDS: 64K + 16K + 2K + 2K + 8K + 1K = 93 KiB -> 1 WG/CU
    __shared__ float pW1[16384];   // pW1[j4*512 + k*4 + jj] = W1[k][j4*4+jj]
    __shared__ float sx[4096];     // x slice [b][s][f]
    __shared__ float zB[512];      // z [b][k]
    __shared__ float hB[512];      // state h [b][j]
    __shared__ float skS[2048];    // k1..k4 [s][b][j]
    __shared__ float sdX[256];     // dX at 4 RK nodes [node][b][f]

    const int t = threadIdx.x;
    const int b_base = blockIdx.x * 4;
    const float dt = 1.0f / 63.0f, rdt = 63.0f;
    const float c13 = dt * (1.0f / 3.0f);

    for (int idx = t; idx < 4096; idx += NT) sx[idx] = x[(size_t)b_base * 1024 + idx];
    for (int idx = t; idx < 16384; idx += NT) {
        const int j4 = idx >> 9, k = (idx >> 2) & 127, jj = idx & 3;
        pW1[idx] = W1[k * 128 + j4 * 4 + jj];
    }
    __syncthreads();

    // h0 = x[:,0] @ Wi^T + bi
    if (t < 512) {
        const int j = t & 127, b = t >> 7;
        float acc = bi[j];
#pragma unroll
        for (int f = 0; f < 16; ++f) acc = fmaf(Wi[j * 16 + f], sx[b * 1024 + f], acc);
        hB[b * 128 + j] = acc;
    }

    // GEMM1 mapping: wave w, lane l -> batch gb, k=gk, j-half jh16
    const int w = t >> 6, l = t & 63;
    const int gb   = w >> 2;
    const int gk   = ((w & 3) << 5) | (l & 31);
    const int jh16 = (l >> 5) << 4;             // j4 base: 0 or 16
    const float b1v = b1[gk];
    const float2 bb = *(const float2*)&b2[t * 2];

    const float4* pw  = PW2 + t;                     // packed: chunk kc at pw[kc*2048], +1024
    const float4* r0p = (const float4*)W2 + t * 64;  // fallback rows
    const float4* r1p = r0p + 32;
    __syncthreads();

    for (int i = 0; i < 63; ++i) {
#pragma unroll
        for (int s = 0; s < 4; ++s) {
            if (s == 0 && t < 256) {
                // Hermite backward-difference coeffs -> dX at 4 RK nodes
                const int f = t & 15, b = (t >> 4) & 3, sn = t >> 6;
                const float* xb = &sx[b * 1024];
                const float x0  = xb[i * 16 + f];
                const float x1  = xb[(i + 1) * 16 + f];
                const float seg = (x1 - x0) * rdt;
                const float m0  = (i == 0) ? seg : (x0 - xb[(i - 1) * 16 + f]) * rdt;
                const float c   = (2.0f * seg - 2.0f * m0) * rdt;
                const float d   = (m0 - seg) * rdt * rdt;
                const float ft  = (float)sn * c13;
                sdX[(sn * 4 + b) * 16 + f] = fmaf(fmaf(3.0f * d, ft, 2.0f * c), ft, m0);
            }
            // ---- GEMM1 (all waves): z[b][k] = tanh(b1 + W1 hs), hs inline from h,k1..k3
            {
                float acc = 0.0f;
                const float* wp  = &pW1[(jh16 * 128 + gk) * 4];
                const float* hp  = &hB[gb * 128 + jh16 * 4];
                const float* k1p = &skS[(0 * 4 + gb) * 128 + jh16 * 4];
                const float* k2p = &skS[(1 * 4 + gb) * 128 + jh16 * 4];
                const float* k3p = &skS[(2 * 4 + gb) * 128 + jh16 * 4];
#pragma unroll
                for (int u = 0; u < 16; ++u) {
                    const float4 wv = *(const float4*)&wp[u * 512];
                    const float4 hv = *(const float4*)&hp[u * 4];
                    float hx = hv.x, hy = hv.y, hz = hv.z, hw = hv.w;
                    if (s == 1) {
                        const float4 k1 = *(const float4*)&k1p[u * 4];
                        hx = fmaf(c13, k1.x, hx); hy = fmaf(c13, k1.y, hy);
                        hz = fmaf(c13, k1.z, hz); hw = fmaf(c13, k1.w, hw);
                    } else if (s == 2) {
                        const float4 k1 = *(const float4*)&k1p[u * 4];
                        const float4 k2 = *(const float4*)&k2p[u * 4];
                        hx = fmaf(dt, k2.x, fmaf(-c13, k1.x, hx));
                        hy = fmaf(dt, k2.y, fmaf(-c13, k1.y, hy));
                        hz = fmaf(dt, k2.z, fmaf(-c13, k1.z, hz));
                        hw = fmaf(dt, k2.w, fmaf(-c13, k1.w, hw));
                    } else if (s == 3) {
                        const float4 k1 = *(const float4*)&k1p[u * 4];
                        const float4 k2 = *(const float4*)&k2p[u * 4];
                        const float4 k3 = *(const float4*)&k3p[u * 4];
                        hx = fmaf(dt, k1.x - k2.x + k3.x, hx);
                        hy = fmaf(dt, k1.y - k2.y + k3.y, hy);
                        hz = fmaf(dt, k1.z - k2.z + k3.z, hz);
                        hw = fmaf(dt, k1.w - k2.w + k3.w, hw);
                    }
                    acc = fmaf(wv.x, hx, acc); acc = fmaf(wv.y, hy, acc);
                    acc = fmaf(wv.z, hz, acc); acc = fmaf(wv.w, hw, acc);
                }
                acc += __shfl_xor(acc, 32);   // combine the two j-halves
                const float zv = tanhf(acc + b1v);
                if (l < 32) zB[gb * 128 + gk] = zv;
            }
            // Issue first two W2 chunks NOW (before the barrier): lgkm barrier
            // doesn't drain vmcnt, so these fly during the barrier wait.
            float4 wa0, wb0, wa1, wb1;
            if (PACKED) {
                wa0 = pw[0 * 2048]; wb0 = pw[0 * 2048 + 1024];
                wa1 = pw[1 * 2048]; wb1 = pw[1 * 2048 + 1024];
            } else {
                wa0 = r0p[0]; wb0 = r1p[0];
                wa1 = r0p[1]; wb1 = r1p[1];
            }
            lgkm_barrier();

            // ---- GEMM2 + F-contraction (rows 2t, 2t+1), depth-2 prefetch
            {
                float a0[4] = {0.f, 0.f, 0.f, 0.f}, a1[4] = {0.f, 0.f, 0.f, 0.f};
#pragma unroll
                for (int kc = 0; kc < 32; ++kc) {
                    const float4 ca = wa0, cb = wb0;
                    wa0 = wa1; wb0 = wb1;
                    if (kc < 30) {
                        if (PACKED) { wa1 = pw[(kc + 2) * 2048]; wb1 = pw[(kc + 2) * 2048 + 1024]; }
                        else        { wa1 = r0p[kc + 2];          wb1 = r1p[kc + 2]; }
                    }
#pragma unroll
                    for (int b = 0; b < 4; ++b) {
                        const float4 z = *(const float4*)&zB[b * 128 + kc * 4]; // uniform b128
                        a0[b] = fmaf(ca.x, z.x, a0[b]); a0[b] = fmaf(ca.y, z.y, a0[b]);
                        a0[b] = fmaf(ca.z, z.z, a0[b]); a0[b] = fmaf(ca.w, z.w, a0[b]);
                        a1[b] = fmaf(cb.x, z.x, a1[b]); a1[b] = fmaf(cb.y, z.y, a1[b]);
                        a1[b] = fmaf(cb.z, z.z, a1[b]); a1[b] = fmaf(cb.w, z.w, a1[b]);
                    }
                }
                const int fp = t & 7, hh = t >> 3;
                float kv[4];
#pragma unroll
                for (int b = 0; b < 4; ++b) {
                    const float2 dx2 = *(const float2*)&sdX[(s * 4 + b) * 16 + fp * 2];
                    kv[b] = (a0[b] + bb.x) * dx2.x + (a1[b] + bb.y) * dx2.y;
                    kv[b] += __shfl_xor(kv[b], 1);
                    kv[b] += __shfl_xor(kv[b], 2);
                    kv[b] += __shfl_xor(kv[b], 4);
                }
                if (fp == 0) {
#pragma unroll
                    for (int b = 0; b < 4; ++b) skS[(s * 4 + b) * 128 + hh] = kv[b];
                }
            }
            lgkm_barrier();
        }
        // ---- h update (once per time step)
        if (t < 512) {
            const int j = t & 127, b = t >> 7;
            const float k1 = skS[(0 * 4 + b) * 128 + j];
            const float k2 = skS[(1 * 4 + b) * 128 + j];
            const float k3 = skS[(2 * 4 + b) * 128 + j];
            const float k4 = skS[(3 * 4 + b) * 128 + j];
            hB[b * 128 + j] = fmaf(dt * 0.125f, k1 + 3.0f * (k2 + k3) + k4, hB[b * 128 + j]);
        }
        lgkm_barrier();
    }

    if (t < 512) {
        const int j = t & 127, b = t >> 7;
        out[(size_t)(b_base + b) * 128 + j] = hB[b * 128 + j];
    }
}

extern "C" void kernel_launch(void* const* d_in, const int* in_sizes, int n_in,
                              void* d_out, int out_size, void* d_ws, size_t ws_size,
                              hipStream_t stream)
{
    (void)in_sizes; (void)n_in; (void)out_size;
    const float* x  = (const float*)d_in[0];
    const float* W1 = (const float*)d_in[1];
    const float* b1 = (const float*)d_in[2];
    const float* W2 = (const float*)d_in[3];
    const float* b2 = (const float*)d_in[4];
    const float* Wi = (const float*)d_in[5];
    const float* bi = (const float*)d_in[6];
    float* o = (float*)d_out;
    float4* PW2 = (float4*)d_ws;
    const bool packed = (ws_size >= (size_t)(2048 * 128 * 4));

    if (packed) {
        hipLaunchKernelGGL(pack_w2_kernel, dim3(256), dim3(256), 0, stream, W2, PW2);
        hipLaunchKernelGGL(HIP_KERNEL_NAME(cde_kernel<true>), dim3(256), dim3(NT), 0, stream,
                           x, W1, b1, W2, b2, Wi, bi, PW2, o);
    } else {
        hipLaunchKernelGGL(HIP_KERNEL_NAME(cde_kernel<false>), dim3(256), dim3(NT), 0, stream,
                           x, W1, b1, W2, b2, Wi, bi, PW2, o);
    }
}

// Round 8
// 6194.365 us; speedup vs baseline: 1.1766x; 1.0416x over previous
//
#include <hip/hip_runtime.h>

// NeuralCDE B=1024,S=64,F=16,H=128. Persistent fp32 kernel, NB=4, 256 wgs.
// Round 8: r2 skeleton (proven 3276us / 52 VGPR / FETCH 6.5MB) — all spill
// suspects removed (no lgkm asm, no fused RK, no persistence, single live
// pointer). Register-lean deltas only:
//   1. PW2 layout [wave][kc,row][lane]: imm-offset addressing (~16 addr
//      bumps/thread/stage vs ~128), coalesced 1KB wave reads.
//   2. All-wave GEMM1 (j-split in-wave + shfl_xor(32)) — no idle waves.
//   3. fast_tanh via v_exp/v_rcp (~8 VALU vs ~35); chunk-0 loads issued
//      before the barrier so L2 latency hides in the barrier wait.
// Empirical law (r2/r4/r6/r7): this shape gets 64 VGPRs, spill = 12+GB HBM.

#define NT 1024

// PW2 float4 slot q = w*4096 + (kc*2+j)*64 + lane,  thread t=w*64+lane owns
// rows 2t (j=0), 2t+1 (j=1);  source = W2[row][kc*4..+3]
__global__ void pack_w2_kernel(const float* __restrict__ W2, float4* __restrict__ PW2) {
    const int q = blockIdx.x * blockDim.x + threadIdx.x;   // 0..65535
    const int lane = q & 63, c = (q >> 6) & 63, w = q >> 12;
    const int kc = c >> 1, j = c & 1;
    const int t = (w << 6) | lane;
    PW2[q] = *(const float4*)&W2[((2 * t + j) << 7) + (kc << 2)];
}

__device__ __forceinline__ float fast_tanh(float x) {
    // tanh(x) = 1 - 2/(e^{2x}+1);  clamp so exp2 can't overflow (tanh(9)=1-1e-8)
    const float xc = fminf(fmaxf(x, -9.0f), 9.0f);
    const float e  = __builtin_amdgcn_exp2f(xc * 2.88539008177792681472f); // 2*log2(e)
    return 1.0f - 2.0f * __builtin_amdgcn_rcpf(e + 1.0f);
}

template<bool PACKED>
__global__ __launch_bounds__(NT) void cde_kernel(
    const float* __restrict__ x,  const float* __restrict__ W1,
    const float* __restrict__ b1, const float* __restrict__ W2,
    const float* __restrict__ b2, const float* __restrict__ Wi,
    const float* __restrict__ bi, const float4* __restrict__ PW2,
    float* __restrict__ out)
{
    // LDS: 64K + 16K + 2K + 2K + 2K + 8K + 1K = 95 KiB -> 1 wg/CU
    __shared__ float pW1[16384];   // pW1[j4*512 + k*4 + jj] = W1[k][j4*4+jj]
    __shared__ float sx[4096];     // x slice [b][s][f]
    __shared__ float zB[512];      // z [b][k]
    __shared__ float hB[512];      // committed state h [b][j]
    __shared__ float hsB[512];     // stage input h_s [b][j]
    __shared__ float skS[2048];    // k1..k4 [s][b][j]
    __shared__ float sdX[256];     // dX at 4 RK nodes [node][b][f]

    const int t = threadIdx.x;
    const int b_base = blockIdx.x * 4;
    const float dt = 1.0f / 63.0f, rdt = 63.0f;
    const float c13 = dt * (1.0f / 3.0f);

    for (int idx = t; idx < 4096; idx += NT) sx[idx] = x[(size_t)b_base * 1024 + idx];
    for (int idx = t; idx < 16384; idx += NT) {
        const int j4 = idx >> 9, k = (idx >> 2) & 127, jj = idx & 3;
        pW1[idx] = W1[k * 128 + j4 * 4 + jj];
    }
    __syncthreads();

    // h0 = x[:,0] @ Wi^T + bi
    if (t < 512) {
        const int j = t & 127, b = t >> 7;
        float acc = bi[j];
#pragma unroll
        for (int f = 0; f < 16; ++f) acc = fmaf(Wi[j * 16 + f], sx[b * 1024 + f], acc);
        hB[b * 128 + j]  = acc;
        hsB[b * 128 + j] = acc;
    }

    // GEMM1 mapping: all 16 waves; lane halves split the j range
    const int w = t >> 6, l = t & 63;
    const int g1b  = w >> 2;                       // batch 0..3
    const int g1k  = ((w & 3) << 5) | (l & 31);    // k 0..127
    const int jh16 = (l >> 5) << 4;                // j4 base: 0 or 16
    const float b1v = b1[g1k];
    const float2 bb = *(const float2*)&b2[t * 2];  // biases rows 2t, 2t+1

    const float4* pb  = PW2 + (w << 12) + l;        // packed per-thread base
    const float4* r0p = (const float4*)W2 + t * 64; // fallback row 2t
    const float4* r1p = r0p + 32;                   // fallback row 2t+1
    __syncthreads();

    for (int i = 0; i < 63; ++i) {
#pragma unroll
        for (int s = 0; s < 4; ++s) {
            if (s == 0 && t < 256) {
                // Hermite backward-difference coeffs -> dX at the 4 RK nodes
                const int f = t & 15, b = (t >> 4) & 3, sn = t >> 6;
                const float* xb = &sx[b * 1024];
                const float x0  = xb[i * 16 + f];
                const float x1  = xb[(i + 1) * 16 + f];
                const float seg = (x1 - x0) * rdt;
                const float m0  = (i == 0) ? seg : (x0 - xb[(i - 1) * 16 + f]) * rdt;
                const float c   = (2.0f * seg - 2.0f * m0) * rdt;
                const float d   = (m0 - seg) * rdt * rdt;
                const float ft  = (float)sn * c13;
                sdX[(sn * 4 + b) * 16 + f] = fmaf(fmaf(3.0f * d, ft, 2.0f * c), ft, m0);
            }
            // ---- GEMM1 (all waves): z[b][k] = tanh(b1 + W1 hs)
            {
                float acc = 0.0f;
                const float* wp = &pW1[(jh16 * 128 + g1k) * 4];   // lane-consec b128
                const float* hp = &hsB[g1b * 128 + jh16 * 4];     // uniform b128
#pragma unroll
                for (int u = 0; u < 16; ++u) {
                    const float4 wv = *(const float4*)&wp[u * 512];
                    const float4 hv = *(const float4*)&hp[u * 4];
                    acc = fmaf(wv.x, hv.x, acc); acc = fmaf(wv.y, hv.y, acc);
                    acc = fmaf(wv.z, hv.z, acc); acc = fmaf(wv.w, hv.w, acc);
                }
                acc += __shfl_xor(acc, 32);            // combine j-halves
                const float zv = fast_tanh(acc + b1v);
                if (l < 32) zB[g1b * 128 + g1k] = zv;  // conflict-free
            }
            // issue chunk-0 W2 loads BEFORE the barrier: latency hides in the wait
            float4 w0, w1;
            if (PACKED) { w0 = pb[0];  w1 = pb[64]; }
            else        { w0 = r0p[0]; w1 = r1p[0]; }
            __syncthreads();

            // ---- GEMM2 + F-contraction (rows 2t, 2t+1), depth-1 prefetch
            {
                float a0[4] = {0.f,0.f,0.f,0.f}, a1[4] = {0.f,0.f,0.f,0.f};
#pragma unroll
                for (int kc = 0; kc < 32; ++kc) {
                    const float4 ca = w0, cb = w1;
                    if (kc < 31) {
                        if (PACKED) { w0 = pb[(kc + 1) * 128]; w1 = pb[(kc + 1) * 128 + 64]; }
                        else        { w0 = r0p[kc + 1];        w1 = r1p[kc + 1]; }
                    }
#pragma unroll
                    for (int b = 0; b < 4; ++b) {
                        const float4 z = *(const float4*)&zB[b * 128 + kc * 4]; // uniform b128
                        a0[b] = fmaf(ca.x, z.x, a0[b]); a0[b] = fmaf(ca.y, z.y, a0[b]);
                        a0[b] = fmaf(ca.z, z.z, a0[b]); a0[b] = fmaf(ca.w, z.w, a0[b]);
                        a1[b] = fmaf(cb.x, z.x, a1[b]); a1[b] = fmaf(cb.y, z.y, a1[b]);
                        a1[b] = fmaf(cb.z, z.z, a1[b]); a1[b] = fmaf(cb.w, z.w, a1[b]);
                    }
                }
                const int fp = t & 7, hh = t >> 3;
                float kv[4];
#pragma unroll
                for (int b = 0; b < 4; ++b) {
                    const float2 dx2 = *(const float2*)&sdX[(s * 4 + b) * 16 + fp * 2];
                    kv[b] = (a0[b] + bb.x) * dx2.x + (a1[b] + bb.y) * dx2.y;
                    kv[b] += __shfl_xor(kv[b], 1);
                    kv[b] += __shfl_xor(kv[b], 2);
                    kv[b] += __shfl_xor(kv[b], 4);
                }
                if (fp == 0) {
#pragma unroll
                    for (int b = 0; b < 4; ++b) skS[(s * 4 + b) * 128 + hh] = kv[b];
                }
            }
            __syncthreads();

            // ---- RK 3/8 stage update (waves 0-7)
            if (t < 512) {
                const int j = t & 127, b = t >> 7;
                const float k1 = skS[(0 * 4 + b) * 128 + j];
                if (s == 3) {
                    const float k2 = skS[(1 * 4 + b) * 128 + j];
                    const float k3 = skS[(2 * 4 + b) * 128 + j];
                    const float k4 = skS[(3 * 4 + b) * 128 + j];
                    const float nh = hB[b * 128 + j]
                                   + dt * 0.125f * (k1 + 3.0f * (k2 + k3) + k4);
                    hB[b * 128 + j]  = nh;
                    hsB[b * 128 + j] = nh;
                } else {
                    const float hv = hB[b * 128 + j];
                    float nh;
                    if (s == 0) {
                        nh = fmaf(c13, k1, hv);
                    } else if (s == 1) {
                        const float k2 = skS[(1 * 4 + b) * 128 + j];
                        nh = hv + dt * k2 - c13 * k1;
                    } else {
                        const float k2 = skS[(1 * 4 + b) * 128 + j];
                        const float k3 = skS[(2 * 4 + b) * 128 + j];
                        nh = fmaf(dt, (k1 - k2 + k3), hv);
                    }
                    hsB[b * 128 + j] = nh;
                }
            }
            __syncthreads();
        }
    }

    if (t < 512) {
        const int j = t & 127, b = t >> 7;
        out[(size_t)(b_base + b) * 128 + j] = hB[b * 128 + j];
    }
}

extern "C" void kernel_launch(void* const* d_in, const int* in_sizes, int n_in,
                              void* d_out, int out_size, void* d_ws, size_t ws_size,
                              hipStream_t stream)
{
    (void)in_sizes; (void)n_in; (void)out_size;
    const float* x  = (const float*)d_in[0];
    const float* W1 = (const float*)d_in[1];
    const float* b1 = (const float*)d_in[2];
    const float* W2 = (const float*)d_in[3];
    const float* b2 = (const float*)d_in[4];
    const float* Wi = (const float*)d_in[5];
    const float* bi = (const float*)d_in[6];
    float* o = (float*)d_out;
    float4* PW2 = (float4*)d_ws;
    const bool packed = (ws_size >= (size_t)(2048 * 128 * 4));

    if (packed) {
        hipLaunchKernelGGL(pack_w2_kernel, dim3(256), dim3(256), 0, stream, W2, PW2);
        hipLaunchKernelGGL(HIP_KERNEL_NAME(cde_kernel<true>), dim3(256), dim3(NT), 0, stream,
                           x, W1, b1, W2, b2, Wi, bi, PW2, o);
    } else {
        hipLaunchKernelGGL(HIP_KERNEL_NAME(cde_kernel<false>), dim3(256), dim3(NT), 0, stream,
                           x, W1, b1, W2, b2, Wi, bi, PW2, o);
    }
}

// Round 9
// 3075.382 us; speedup vs baseline: 2.3700x; 2.0142x over previous
//
#include <hip/hip_runtime.h>

// NeuralCDE B=1024,S=64,F=16,H=128. Persistent fp32 kernel, NB=4, 256 wgs.
// Round 9: r8 minus the spill trigger. r2..r8 post-mortem series:
//   r2 (unroll 2 on kc, no s-unroll)      -> 52 VGPR, FETCH 6.5 MB, 3276 us
//   r4/r6/r7/r8 (full kc and/or s unroll) -> 64 VGPR + 12-21 GB scratch HBM
// Diagnosis: full unroll lets the scheduler hoist global loads across a
// 128-iteration flat body; live-set blows past the allocator's fixed 64-VGPR
// target at NT=1024 -> spill. Fix: restore r2 unroll discipline
// (s-loop unroll 1, kc unroll 2, GEMM1 unroll 8). Keep r8's cheap deltas:
// PW2 imm-offset layout, all-wave GEMM1, fast_tanh, pre-barrier chunk-0 issue.

#define NT 1024

// PW2 float4 slot q = w*4096 + (kc*2+j)*64 + lane; thread t=w*64+lane owns
// rows 2t (j=0), 2t+1 (j=1); source = W2[row][kc*4..+3]
__global__ void pack_w2_kernel(const float* __restrict__ W2, float4* __restrict__ PW2) {
    const int q = blockIdx.x * blockDim.x + threadIdx.x;   // 0..65535
    const int lane = q & 63, c = (q >> 6) & 63, w = q >> 12;
    const int kc = c >> 1, j = c & 1;
    const int t = (w << 6) | lane;
    PW2[q] = *(const float4*)&W2[((2 * t + j) << 7) + (kc << 2)];
}

__device__ __forceinline__ float fast_tanh(float x) {
    // tanh(x) = 1 - 2/(e^{2x}+1); clamp so exp2 can't overflow (tanh(9)=1-1e-8)
    const float xc = fminf(fmaxf(x, -9.0f), 9.0f);
    const float e  = __builtin_amdgcn_exp2f(xc * 2.88539008177792681472f); // 2x*log2(e)
    return 1.0f - 2.0f * __builtin_amdgcn_rcpf(e + 1.0f);
}

template<bool PACKED>
__global__ __launch_bounds__(NT) void cde_kernel(
    const float* __restrict__ x,  const float* __restrict__ W1,
    const float* __restrict__ b1, const float* __restrict__ W2,
    const float* __restrict__ b2, const float* __restrict__ Wi,
    const float* __restrict__ bi, const float4* __restrict__ PW2,
    float* __restrict__ out)
{
    // LDS: 64K + 16K + 2K + 2K + 2K + 8K + 1K = 95 KiB -> 1 wg/CU
    __shared__ float pW1[16384];   // pW1[j4*512 + k*4 + jj] = W1[k][j4*4+jj]
    __shared__ float sx[4096];     // x slice [b][s][f]
    __shared__ float zB[512];      // z [b][k]
    __shared__ float hB[512];      // committed state h [b][j]
    __shared__ float hsB[512];     // stage input h_s [b][j]
    __shared__ float skS[2048];    // k1..k4 [s][b][j]
    __shared__ float sdX[256];     // dX at 4 RK nodes [node][b][f]

    const int t = threadIdx.x;
    const int b_base = blockIdx.x * 4;
    const float dt = 1.0f / 63.0f, rdt = 63.0f;
    const float c13 = dt * (1.0f / 3.0f);

    for (int idx = t; idx < 4096; idx += NT) sx[idx] = x[(size_t)b_base * 1024 + idx];
    for (int idx = t; idx < 16384; idx += NT) {
        const int j4 = idx >> 9, k = (idx >> 2) & 127, jj = idx & 3;
        pW1[idx] = W1[k * 128 + j4 * 4 + jj];
    }
    __syncthreads();

    // h0 = x[:,0] @ Wi^T + bi
    if (t < 512) {
        const int j = t & 127, b = t >> 7;
        float acc = bi[j];
#pragma unroll
        for (int f = 0; f < 16; ++f) acc = fmaf(Wi[j * 16 + f], sx[b * 1024 + f], acc);
        hB[b * 128 + j]  = acc;
        hsB[b * 128 + j] = acc;
    }

    // GEMM1 mapping: all 16 waves; lane halves split the j range
    const int w = t >> 6, l = t & 63;
    const int g1b  = w >> 2;                       // batch 0..3
    const int g1k  = ((w & 3) << 5) | (l & 31);    // k 0..127
    const int jh16 = (l >> 5) << 4;                // j4 base: 0 or 16
    const float b1v = b1[g1k];
    const float2 bb = *(const float2*)&b2[t * 2];  // biases rows 2t, 2t+1

    const float4* pb  = PW2 + (w << 12) + l;        // packed per-thread base
    const float4* r0p = (const float4*)W2 + t * 64; // fallback row 2t
    const float4* r1p = r0p + 32;                   // fallback row 2t+1
    __syncthreads();

    for (int i = 0; i < 63; ++i) {
#pragma unroll 1
        for (int s = 0; s < 4; ++s) {
            if (s == 0 && t < 256) {
                // Hermite backward-difference coeffs -> dX at the 4 RK nodes
                const int f = t & 15, b = (t >> 4) & 3, sn = t >> 6;
                const float* xb = &sx[b * 1024];
                const float x0  = xb[i * 16 + f];
                const float x1  = xb[(i + 1) * 16 + f];
                const float seg = (x1 - x0) * rdt;
                const float m0  = (i == 0) ? seg : (x0 - xb[(i - 1) * 16 + f]) * rdt;
                const float c   = (2.0f * seg - 2.0f * m0) * rdt;
                const float d   = (m0 - seg) * rdt * rdt;
                const float ft  = (float)sn * c13;
                sdX[(sn * 4 + b) * 16 + f] = fmaf(fmaf(3.0f * d, ft, 2.0f * c), ft, m0);
            }
            // ---- GEMM1 (all waves): z[b][k] = tanh(b1 + W1 hs)
            {
                float acc = 0.0f;
                const float* wp = &pW1[(jh16 * 128 + g1k) * 4];   // lane-consec b128
                const float* hp = &hsB[g1b * 128 + jh16 * 4];     // uniform b128
#pragma unroll 8
                for (int u = 0; u < 16; ++u) {
                    const float4 wv = *(const float4*)&wp[u * 512];
                    const float4 hv = *(const float4*)&hp[u * 4];
                    acc = fmaf(wv.x, hv.x, acc); acc = fmaf(wv.y, hv.y, acc);
                    acc = fmaf(wv.z, hv.z, acc); acc = fmaf(wv.w, hv.w, acc);
                }
                acc += __shfl_xor(acc, 32);            // combine j-halves
                const float zv = fast_tanh(acc + b1v);
                if (l < 32) zB[g1b * 128 + g1k] = zv;  // conflict-free
            }
            // issue chunk-0 W2 loads BEFORE the barrier: latency hides in the wait
            float4 w0, w1;
            if (PACKED) { w0 = pb[0];  w1 = pb[64]; }
            else        { w0 = r0p[0]; w1 = r1p[0]; }
            __syncthreads();

            // ---- GEMM2 + F-contraction (rows 2t, 2t+1), depth-1 prefetch
            {
                float a0[4] = {0.f,0.f,0.f,0.f}, a1[4] = {0.f,0.f,0.f,0.f};
#pragma unroll 2
                for (int kc = 0; kc < 32; ++kc) {
                    const float4 ca = w0, cb = w1;
                    if (kc < 31) {
                        if (PACKED) { w0 = pb[(kc + 1) * 128]; w1 = pb[(kc + 1) * 128 + 64]; }
                        else        { w0 = r0p[kc + 1];        w1 = r1p[kc + 1]; }
                    }
#pragma unroll
                    for (int b = 0; b < 4; ++b) {
                        const float4 z = *(const float4*)&zB[b * 128 + kc * 4]; // uniform b128
                        a0[b] = fmaf(ca.x, z.x, a0[b]); a0[b] = fmaf(ca.y, z.y, a0[b]);
                        a0[b] = fmaf(ca.z, z.z, a0[b]); a0[b] = fmaf(ca.w, z.w, a0[b]);
                        a1[b] = fmaf(cb.x, z.x, a1[b]); a1[b] = fmaf(cb.y, z.y, a1[b]);
                        a1[b] = fmaf(cb.z, z.z, a1[b]); a1[b] = fmaf(cb.w, z.w, a1[b]);
                    }
                }
                const int fp = t & 7, hh = t >> 3;
                float kv[4];
#pragma unroll
                for (int b = 0; b < 4; ++b) {
                    const float2 dx2 = *(const float2*)&sdX[(s * 4 + b) * 16 + fp * 2];
                    kv[b] = (a0[b] + bb.x) * dx2.x + (a1[b] + bb.y) * dx2.y;
                    kv[b] += __shfl_xor(kv[b], 1);
                    kv[b] += __shfl_xor(kv[b], 2);
                    kv[b] += __shfl_xor(kv[b], 4);
                }
                if (fp == 0) {
#pragma unroll
                    for (int b = 0; b < 4; ++b) skS[(s * 4 + b) * 128 + hh] = kv[b];
                }
            }
            __syncthreads();

            // ---- RK 3/8 stage update (waves 0-7)
            if (t < 512) {
                const int j = t & 127, b = t >> 7;
                const float k1 = skS[(0 * 4 + b) * 128 + j];
                if (s == 3) {
                    const float k2 = skS[(1 * 4 + b) * 128 + j];
                    const float k3 = skS[(2 * 4 + b) * 128 + j];
                    const float k4 = skS[(3 * 4 + b) * 128 + j];
                    const float nh = hB[b * 128 + j]
                                   + dt * 0.125f * (k1 + 3.0f * (k2 + k3) + k4);
                    hB[b * 128 + j]  = nh;
                    hsB[b * 128 + j] = nh;
                } else {
                    const float hv = hB[b * 128 + j];
                    float nh;
                    if (s == 0) {
                        nh = fmaf(c13, k1, hv);
                    } else if (s == 1) {
                        const float k2 = skS[(1 * 4 + b) * 128 + j];
                        nh = hv + dt * k2 - c13 * k1;
                    } else {
                        const float k2 = skS[(1 * 4 + b) * 128 + j];
                        const float k3 = skS[(2 * 4 + b) * 128 + j];
                        nh = fmaf(dt, (k1 - k2 + k3), hv);
                    }
                    hsB[b * 128 + j] = nh;
                }
            }
            __syncthreads();
        }
    }

    if (t < 512) {
        const int j = t & 127, b = t >> 7;
        out[(size_t)(b_base + b) * 128 + j] = hB[b * 128 + j];
    }
}

extern "C" void kernel_launch(void* const* d_in, const int* in_sizes, int n_in,
                              void* d_out, int out_size, void* d_ws, size_t ws_size,
                              hipStream_t stream)
{
    (void)in_sizes; (void)n_in; (void)out_size;
    const float* x  = (const float*)d_in[0];
    const float* W1 = (const float*)d_in[1];
    const float* b1 = (const float*)d_in[2];
    const float* W2 = (const float*)d_in[3];
    const float* b2 = (const float*)d_in[4];
    const float* Wi = (const float*)d_in[5];
    const float* bi = (const float*)d_in[6];
    float* o = (float*)d_out;
    float4* PW2 = (float4*)d_ws;
    const bool packed = (ws_size >= (size_t)(2048 * 128 * 4));

    if (packed) {
        hipLaunchKernelGGL(pack_w2_kernel, dim3(256), dim3(256), 0, stream, W2, PW2);
        hipLaunchKernelGGL(HIP_KERNEL_NAME(cde_kernel<true>), dim3(256), dim3(NT), 0, stream,
                           x, W1, b1, W2, b2, Wi, bi, PW2, o);
    } else {
        hipLaunchKernelGGL(HIP_KERNEL_NAME(cde_kernel<false>), dim3(256), dim3(NT), 0, stream,
                           x, W1, b1, W2, b2, Wi, bi, PW2, o);
    }
}